// Round 2
// baseline (522.462 us; speedup 1.0000x reference)
//
#include <hip/hip_runtime.h>

#define NNODES 20000
#define NEDGES 200000

// ---------------------------------------------------------------------------
// Zero-fill (float4 granularity). n4 = number of float4 elements.
// ---------------------------------------------------------------------------
__global__ __launch_bounds__(256)
void zero_kernel(float4* __restrict__ p, long n4)
{
    long i = (long)blockIdx.x * 256 + threadIdx.x;
    if (i < n4) p[i] = make_float4(0.f, 0.f, 0.f, 0.f);
}

// ---------------------------------------------------------------------------
// CSR build, both directions batched via blockIdx.y / blockIdx.x(scan):
// histogram -> single-block-per-direction scan -> scatter
// ---------------------------------------------------------------------------
__global__ __launch_bounds__(256)
void hist2_kernel(const int* __restrict__ dst0, const int* __restrict__ dst1,
                  int* __restrict__ deg0, int* __restrict__ deg1, int n)
{
    const int e = blockIdx.x * 256 + threadIdx.x;
    if (e >= n) return;
    if (blockIdx.y == 0) atomicAdd(&deg0[dst0[e]], 1);
    else                 atomicAdd(&deg1[dst1[e]], 1);
}

__global__ __launch_bounds__(1024)
void scan2_kernel(const int* __restrict__ deg0, const int* __restrict__ deg1,
                  int* __restrict__ rp0, int* __restrict__ rp1,
                  int* __restrict__ cur0, int* __restrict__ cur1, int n)
{
    const int* deg = blockIdx.x == 0 ? deg0 : deg1;
    int* rowptr    = blockIdx.x == 0 ? rp0  : rp1;
    int* cursor    = blockIdx.x == 0 ? cur0 : cur1;

    __shared__ int part[1024];
    const int t  = threadIdx.x;
    const int CH = (n + 1023) / 1024;
    const int base = t * CH;

    int s = 0;
    for (int i = 0; i < CH; ++i) {
        int idx = base + i;
        if (idx < n) s += deg[idx];
    }
    part[t] = s;
    __syncthreads();
    for (int off = 1; off < 1024; off <<= 1) {
        int v = 0;
        if (t >= off) v = part[t - off];
        __syncthreads();
        if (t >= off) part[t] += v;
        __syncthreads();
    }
    int run = (t == 0) ? 0 : part[t - 1];
    for (int i = 0; i < CH; ++i) {
        int idx = base + i;
        if (idx < n) {
            int dv = deg[idx];
            rowptr[idx] = run;
            cursor[idx] = run;
            run += dv;
        }
    }
    if (t == 1023) rowptr[n] = part[1023];
}

__global__ __launch_bounds__(256)
void scatter2_kernel(const int* __restrict__ dst0, const int* __restrict__ dst1,
                     int* __restrict__ cur0, int* __restrict__ cur1,
                     int* __restrict__ ei0, int* __restrict__ ei1, int n)
{
    const int e = blockIdx.x * 256 + threadIdx.x;
    if (e >= n) return;
    if (blockIdx.y == 0) { int p = atomicAdd(&cur0[dst0[e]], 1); ei0[p] = e; }
    else                 { int p = atomicAdd(&cur1[dst1[e]], 1); ei1[p] = e; }
}

// ---------------------------------------------------------------------------
// Segmented attention-aggregation v3 (unchanged this round).
// ---------------------------------------------------------------------------
__global__ __launch_bounds__(128)
void agg3_kernel(const float* __restrict__ fn0, const float* __restrict__ fe0,
                 const float* __restrict__ ha0, const int* __restrict__ src0,
                 const int* __restrict__ ei0,  const int* __restrict__ rp0,
                 float* __restrict__ agg0,
                 const float* __restrict__ fn1, const float* __restrict__ fe1,
                 const float* __restrict__ ha1, const int* __restrict__ src1,
                 const int* __restrict__ ei1,  const int* __restrict__ rp1,
                 float* __restrict__ agg1)
{
    const int y = blockIdx.y;
    const float* __restrict__ feat_node = y == 0 ? fn0 : fn1;
    const float* __restrict__ feat_edge = y == 0 ? fe0 : fe1;
    const float* __restrict__ h_att     = y == 0 ? ha0 : ha1;
    const int*   __restrict__ src       = y == 0 ? src0 : src1;
    const int*   __restrict__ eidx      = y == 0 ? ei0 : ei1;
    const int*   __restrict__ rowptr    = y == 0 ? rp0 : rp1;
    float*       __restrict__ agg       = y == 0 ? agg0 : agg1;

    const int d = blockIdx.x;
    const int c = threadIdx.x;
    const int lo = rowptr[d], hi = rowptr[d + 1];
    const bool low = c < 64;

    __shared__ int se[64];
    __shared__ int ss[64];

    float ssum = 0.f, anum = 0.f;

    for (int base = lo; base < hi; base += 64) {
        const int cnt = min(64, hi - base);
        if (c < cnt) {
            const int e = eidx[base + c];
            se[c] = e;
            ss[c] = src[e];
        }
        __syncthreads();

        int i = 0;
        for (; i + 4 <= cnt; i += 4) {
            float hv[4], at[4];
            #pragma unroll
            for (int j = 0; j < 4; ++j) {
                const int e = se[i + j];
                const int s = ss[i + j];
                hv[j] = low ? feat_node[(long)s * 64 + c]
                            : feat_edge[(long)e * 64 + (c - 64)];
                at[j] = h_att[(long)s * 128 + c];
            }
            #pragma unroll
            for (int j = 0; j < 4; ++j) {
                const float p = __expf(hv[j] * at[j]);
                ssum += p;
                anum += hv[j] * p;
            }
        }
        for (; i < cnt; ++i) {
            const int e = se[i];
            const int s = ss[i];
            const float hvv = low ? feat_node[(long)s * 64 + c]
                                  : feat_edge[(long)e * 64 + (c - 64)];
            const float att = h_att[(long)s * 128 + c];
            const float p = __expf(hvv * att);
            ssum += p;
            anum += hvv * p;
        }
        __syncthreads();
    }
    agg[(long)d * 128 + c] = (hi > lo) ? anum / ssum : 0.f;
}

// ---------------------------------------------------------------------------
// Round-7 GEMM microkernel family: 8x8 per-thread micro-tile, BLOCK=128.
// Rationale (round-6 rocprof): 4x4 tile moves 2 operand-bytes/FMA through the
// ~128 B/cyc LDS/L1 return buses -> VALUBusy pinned at 40% (measured 41).
// 8x8 is 1 B/FMA = the VALU/LDS balance point. Occupancy drops to 3 blocks/CU
// on purpose; the 256-FMA inner block provides the ILP.
// LDS layouts (conflict-free):
//   x: k-quad slabs xs4[kv][slot], slot(rr)=(rr&3)*BQ+(rr>>2)
//      -> staging b128 writes at the write floor; reads: 8 b128/quad, <=2-way.
//   W: Ws[k][sigma(c4)], sigma(c4)=(c4&1)*JT+(c4>>1)
//      -> read start banks spread by 4*jt, <=2-way.
// ---------------------------------------------------------------------------
struct LinArgs {
    const float* x[5];
    const float* W[5];
    const float* bias[5];
    float*       out[5];
    long         ostride[5];
};

template<int DOUT, bool RELU>
__global__ __launch_bounds__(128)
void lin8_kernel(LinArgs a, int nrows)
{
    constexpr int BLOCK = 128;
    constexpr int DIN = 64;
    constexpr int KV  = DIN / 4;        // 16 k-quads
    constexpr int JT  = DOUT / 8;       // col groups (8 or 16)
    constexpr int RT  = BLOCK / JT;     // row groups (16 or 8)
    constexpr int BR  = RT * 8;         // rows per block (128 or 64)
    constexpr int BQ  = BR / 4;         // row-quads
    constexpr int XSTR = BR + 1;        // float4 stride per kv slab
    constexpr int WSTR = DOUT + 4;      // float stride per W row

    const int y = blockIdx.y;
    const float* __restrict__ x    = a.x[y];
    const float* __restrict__ W    = a.W[y];
    const float* __restrict__ bias = a.bias[y];
    float* __restrict__ out        = a.out[y];
    const long ostride             = a.ostride[y];

    __shared__ float4 xs4[KV * XSTR];
    __shared__ float  Ws[DIN * WSTR];

    const int tid  = threadIdx.x;
    const int row0 = blockIdx.x * BR;

    // stage W (column-quad slot permute)
    const float4* __restrict__ W4 = (const float4*)W;
    for (int i = tid; i < DIN * DOUT / 4; i += BLOCK) {
        const int k = i / (DOUT / 4), c4 = i % (DOUT / 4);
        ((float4*)(Ws + k * WSTR))[(c4 & 1) * JT + (c4 >> 1)] = W4[i];
    }
    // stage x (k-quad slabs, row-slot permute); coalesced global reads
    const float4* __restrict__ X4 = (const float4*)x;
    for (int i = tid; i < BR * KV; i += BLOCK) {
        const int rr = i >> 4, kv = i & 15;
        const int row = row0 + rr;
        float4 v = make_float4(0.f, 0.f, 0.f, 0.f);
        if (row < nrows) v = X4[(long)row * KV + kv];
        xs4[kv * XSTR + (rr & 3) * BQ + (rr >> 2)] = v;
    }
    __syncthreads();

    const int jt = tid % JT;
    const int rt = tid / JT;

    float4 b0 = ((const float4*)bias)[jt * 2];
    float4 b1 = ((const float4*)bias)[jt * 2 + 1];
    float acc[8][8];
    #pragma unroll
    for (int r = 0; r < 8; ++r) {
        acc[r][0] = b0.x; acc[r][1] = b0.y; acc[r][2] = b0.z; acc[r][3] = b0.w;
        acc[r][4] = b1.x; acc[r][5] = b1.y; acc[r][6] = b1.z; acc[r][7] = b1.w;
    }

    #pragma unroll 2
    for (int kv = 0; kv < KV; ++kv) {
        float4 xq[8];
        #pragma unroll
        for (int r = 0; r < 8; ++r)
            xq[r] = xs4[kv * XSTR + (r & 3) * BQ + rt * 2 + (r >> 2)];
        #pragma unroll
        for (int q = 0; q < 4; ++q) {
            const int k = kv * 4 + q;
            float4 wa = ((const float4*)(Ws + k * WSTR))[jt];
            float4 wb = ((const float4*)(Ws + k * WSTR))[JT + jt];
            const float wc[8] = {wa.x, wa.y, wa.z, wa.w, wb.x, wb.y, wb.z, wb.w};
            #pragma unroll
            for (int r = 0; r < 8; ++r) {
                const float xk = q == 0 ? xq[r].x : q == 1 ? xq[r].y
                               : q == 2 ? xq[r].z : xq[r].w;
                #pragma unroll
                for (int c = 0; c < 8; ++c)
                    acc[r][c] = fmaf(xk, wc[c], acc[r][c]);
            }
        }
    }

    #pragma unroll
    for (int r = 0; r < 8; ++r) {
        const int row = row0 + rt * 8 + r;
        if (row >= nrows) continue;
        float4 o0 = make_float4(acc[r][0], acc[r][1], acc[r][2], acc[r][3]);
        float4 o1 = make_float4(acc[r][4], acc[r][5], acc[r][6], acc[r][7]);
        if (RELU) {
            o0.x = fmaxf(o0.x, 0.f); o0.y = fmaxf(o0.y, 0.f);
            o0.z = fmaxf(o0.z, 0.f); o0.w = fmaxf(o0.w, 0.f);
            o1.x = fmaxf(o1.x, 0.f); o1.y = fmaxf(o1.y, 0.f);
            o1.z = fmaxf(o1.z, 0.f); o1.w = fmaxf(o1.w, 0.f);
        }
        float4* op = (float4*)(out + (long)row * ostride);
        op[jt * 2]     = o0;
        op[jt * 2 + 1] = o1;
    }
}

// ---------------------------------------------------------------------------
// Edge kernel, same 8x8 structure (DIN=DOUT=64) + gather epilogue:
//   out = relu(x @ W + b + tabA[idxA[r]] + tabB[idxB[r]])
// ---------------------------------------------------------------------------
struct EdgeArgs {
    const float* x[2];
    const float* tabA[2];
    const float* tabB[2];
    const int*   idxA[2];
    const int*   idxB[2];
    float*       out[2];
};

__global__ __launch_bounds__(128)
void edge8_kernel(EdgeArgs a, const float* __restrict__ W,
                  const float* __restrict__ bias, int nrows)
{
    constexpr int BLOCK = 128;
    constexpr int DIN = 64, DOUT = 64;
    constexpr int KV  = 16;
    constexpr int JT  = 8;
    constexpr int BR  = 128;
    constexpr int BQ  = 32;
    constexpr int XSTR = BR + 1;    // 129
    constexpr int WSTR = DOUT + 4;  // 68

    const int y = blockIdx.y;
    const float* __restrict__ x    = a.x[y];
    const float* __restrict__ tabA = a.tabA[y];
    const float* __restrict__ tabB = a.tabB[y];
    const int* __restrict__ idxA   = a.idxA[y];
    const int* __restrict__ idxB   = a.idxB[y];
    float* __restrict__ out        = a.out[y];

    __shared__ float4 xs4[KV * XSTR];
    __shared__ float  Ws[DIN * WSTR];

    const int tid  = threadIdx.x;
    const int row0 = blockIdx.x * BR;

    const float4* __restrict__ W4 = (const float4*)W;
    for (int i = tid; i < DIN * DOUT / 4; i += BLOCK) {
        const int k = i / (DOUT / 4), c4 = i % (DOUT / 4);
        ((float4*)(Ws + k * WSTR))[(c4 & 1) * JT + (c4 >> 1)] = W4[i];
    }
    const float4* __restrict__ X4 = (const float4*)x;
    for (int i = tid; i < BR * KV; i += BLOCK) {
        const int rr = i >> 4, kv = i & 15;
        const int row = row0 + rr;
        float4 v = make_float4(0.f, 0.f, 0.f, 0.f);
        if (row < nrows) v = X4[(long)row * KV + kv];
        xs4[kv * XSTR + (rr & 3) * BQ + (rr >> 2)] = v;
    }
    __syncthreads();

    const int jt = tid % JT;
    const int rt = tid / JT;

    float4 b0 = ((const float4*)bias)[jt * 2];
    float4 b1 = ((const float4*)bias)[jt * 2 + 1];
    float acc[8][8];
    #pragma unroll
    for (int r = 0; r < 8; ++r) {
        acc[r][0] = b0.x; acc[r][1] = b0.y; acc[r][2] = b0.z; acc[r][3] = b0.w;
        acc[r][4] = b1.x; acc[r][5] = b1.y; acc[r][6] = b1.z; acc[r][7] = b1.w;
    }

    #pragma unroll 2
    for (int kv = 0; kv < KV; ++kv) {
        float4 xq[8];
        #pragma unroll
        for (int r = 0; r < 8; ++r)
            xq[r] = xs4[kv * XSTR + (r & 3) * BQ + rt * 2 + (r >> 2)];
        #pragma unroll
        for (int q = 0; q < 4; ++q) {
            const int k = kv * 4 + q;
            float4 wa = ((const float4*)(Ws + k * WSTR))[jt];
            float4 wb = ((const float4*)(Ws + k * WSTR))[JT + jt];
            const float wc[8] = {wa.x, wa.y, wa.z, wa.w, wb.x, wb.y, wb.z, wb.w};
            #pragma unroll
            for (int r = 0; r < 8; ++r) {
                const float xk = q == 0 ? xq[r].x : q == 1 ? xq[r].y
                               : q == 2 ? xq[r].z : xq[r].w;
                #pragma unroll
                for (int c = 0; c < 8; ++c)
                    acc[r][c] = fmaf(xk, wc[c], acc[r][c]);
            }
        }
    }

    // epilogue: issue all idx loads first, then per-row gathers + store
    int ia[8], ib[8];
    #pragma unroll
    for (int r = 0; r < 8; ++r) {
        const int row = row0 + rt * 8 + r;
        ia[r] = (row < nrows) ? idxA[row] : 0;
        ib[r] = (row < nrows) ? idxB[row] : 0;
    }
    #pragma unroll
    for (int r = 0; r < 8; ++r) {
        const int row = row0 + rt * 8 + r;
        if (row >= nrows) continue;
        const float4* tA = (const float4*)(tabA + (long)ia[r] * 64);
        const float4* tB = (const float4*)(tabB + (long)ib[r] * 64);
        float4 ga0 = tA[jt * 2], ga1 = tA[jt * 2 + 1];
        float4 gb0 = tB[jt * 2], gb1 = tB[jt * 2 + 1];
        float4 o0, o1;
        o0.x = fmaxf(acc[r][0] + ga0.x + gb0.x, 0.f);
        o0.y = fmaxf(acc[r][1] + ga0.y + gb0.y, 0.f);
        o0.z = fmaxf(acc[r][2] + ga0.z + gb0.z, 0.f);
        o0.w = fmaxf(acc[r][3] + ga0.w + gb0.w, 0.f);
        o1.x = fmaxf(acc[r][4] + ga1.x + gb1.x, 0.f);
        o1.y = fmaxf(acc[r][5] + ga1.y + gb1.y, 0.f);
        o1.z = fmaxf(acc[r][6] + ga1.z + gb1.z, 0.f);
        o1.w = fmaxf(acc[r][7] + ga1.w + gb1.w, 0.f);
        float4* op = (float4*)(out + (long)row * 64);
        op[jt * 2]     = o0;
        op[jt * 2 + 1] = o1;
    }
}

// ---------------------------------------------------------------------------
// Small 4x4 template for the 128->64 final linear (its 8x8 LDS footprint
// would not fit). W from global (L1-resident), xs col-major stride BR+1
// (2-way-max staging conflicts), 4x b32 broadcast reads.
// ---------------------------------------------------------------------------
template<int DIN, int DOUT, int BLOCK, bool RELU>
__global__ __launch_bounds__(BLOCK)
void lin_small_kernel(LinArgs a, int nrows)
{
    constexpr int BR  = 16 * BLOCK / DOUT;   // 32 for <128,64,128>
    constexpr int BRP = BR + 1;
    constexpr int KV  = DIN / 4;
    constexpr int JT  = DOUT / 4;

    const int y = blockIdx.y;
    const float* __restrict__ x    = a.x[y];
    const float* __restrict__ W    = a.W[y];
    const float* __restrict__ bias = a.bias[y];
    float* __restrict__ out        = a.out[y];
    const long ostride             = a.ostride[y];

    __shared__ float xs[DIN * BRP];

    const int tid  = threadIdx.x;
    const int row0 = blockIdx.x * BR;

    const int kv = tid % KV;
    for (int rr = tid / KV; rr < BR; rr += BLOCK / KV) {
        const int row = row0 + rr;
        float4 v = make_float4(0.f, 0.f, 0.f, 0.f);
        if (row < nrows)
            v = ((const float4*)x)[(long)row * KV + kv];
        xs[(kv * 4 + 0) * BRP + rr] = v.x;
        xs[(kv * 4 + 1) * BRP + rr] = v.y;
        xs[(kv * 4 + 2) * BRP + rr] = v.z;
        xs[(kv * 4 + 3) * BRP + rr] = v.w;
    }
    __syncthreads();

    const int jt = tid % JT;
    const int rt = tid / JT;

    float4 b4 = ((const float4*)bias)[jt];
    float acc[4][4];
    #pragma unroll
    for (int r = 0; r < 4; ++r) {
        acc[r][0] = b4.x; acc[r][1] = b4.y; acc[r][2] = b4.z; acc[r][3] = b4.w;
    }

    const float4* __restrict__ W4 = (const float4*)W;
    #pragma unroll 4
    for (int k = 0; k < DIN; ++k) {
        float4 w = W4[k * JT + jt];
        float xr[4];
        #pragma unroll
        for (int r = 0; r < 4; ++r) xr[r] = xs[k * BRP + rt * 4 + r];
        #pragma unroll
        for (int r = 0; r < 4; ++r) {
            acc[r][0] = fmaf(xr[r], w.x, acc[r][0]);
            acc[r][1] = fmaf(xr[r], w.y, acc[r][1]);
            acc[r][2] = fmaf(xr[r], w.z, acc[r][2]);
            acc[r][3] = fmaf(xr[r], w.w, acc[r][3]);
        }
    }

    #pragma unroll
    for (int r = 0; r < 4; ++r) {
        const int row = row0 + rt * 4 + r;
        if (row >= nrows) continue;
        float4 o = make_float4(acc[r][0], acc[r][1], acc[r][2], acc[r][3]);
        if (RELU) {
            o.x = fmaxf(o.x, 0.f); o.y = fmaxf(o.y, 0.f);
            o.z = fmaxf(o.z, 0.f); o.w = fmaxf(o.w, 0.f);
        }
        *((float4*)(out + (long)row * ostride) + jt) = o;
    }
}

// ---------------------------------------------------------------------------
extern "C" void kernel_launch(void* const* d_in, const int* in_sizes, int n_in,
                              void* d_out, int out_size, void* d_ws, size_t ws_size,
                              hipStream_t stream)
{
    const float* f_feat = (const float*)d_in[0];
    const float* b_feat = (const float*)d_in[1];
    const float* u_feat = (const float*)d_in[2];
    const float* v_feat = (const float*)d_in[3];
    const int* fw_src = (const int*)d_in[4];
    const int* fw_dst = (const int*)d_in[5];
    const int* bw_src = (const int*)d_in[6];
    const int* bw_dst = (const int*)d_in[7];
    const float* w_e  = (const float*)d_in[8];   const float* b_e  = (const float*)d_in[9];
    const float* w_u  = (const float*)d_in[10];  const float* b_u  = (const float*)d_in[11];
    const float* w_v  = (const float*)d_in[12];  const float* b_v  = (const float*)d_in[13];
    const float* w_au = (const float*)d_in[14];  const float* b_au = (const float*)d_in[15];
    const float* w_av = (const float*)d_in[16];  const float* b_av = (const float*)d_in[17];
    const float* w_Wu = (const float*)d_in[18];  const float* b_Wu = (const float*)d_in[19];
    const float* w_Wv = (const float*)d_in[20];  const float* b_Wv = (const float*)d_in[21];
    const float* w_Vu = (const float*)d_in[22];  const float* b_Vu = (const float*)d_in[23];
    const float* w_Vv = (const float*)d_in[24];  const float* b_Vv = (const float*)d_in[25];

    const int N = NNODES, E = NEDGES;

    // outputs: (hf, hb, hu, hv) concatenated flat
    float* out = (float*)d_out;
    float* hf = out;                       // [E,64]  (written LAST)
    float* hb = hf + (long)E * 64;         // [E,64]  (written LAST)
    float* hu = hb + (long)E * 64;         // [N,128]
    float* hv = hu + (long)N * 128;        // [N,128]

    // h_att_u / h_att_v staged in the hf region of d_out (2*N*128 floats
    // < E*64). Consumed by agg, then hf overwritten by the edge batch LAST.
    float* h_att_u = hf;                   // [N,128]
    float* h_att_v = h_att_u + (long)N * 128;

    // workspace: floats 3*N*64 + 2*N*128 = 8.96M; ints 6N+2+2E = 0.52M
    float* ws = (float*)d_ws;
    float* src_he_u = ws;                        // [N,64] (== dst_he_u)
    float* src_he_v = src_he_u + (long)N * 64;   // [N,64]
    float* dst_he_v = src_he_v + (long)N * 64;   // [N,64]
    float* agg_u    = dst_he_v + (long)N * 64;   // [N,128]
    float* agg_v    = agg_u    + (long)N * 128;  // [N,128]
    int*   ibase    = (int*)(agg_v + (long)N * 128);
    int* deg_b    = ibase;                 // [N] zeroed
    int* deg_f    = deg_b + N;             // [N] zeroed
    int* rowptr_b = deg_f + N;             // [N+1]
    int* rowptr_f = rowptr_b + (N + 1);    // [N+1]
    int* cursor_b = rowptr_f + (N + 1);    // [N]
    int* cursor_f = cursor_b + N;          // [N]
    int* eidx_b   = cursor_f + N;          // [E]
    int* eidx_f   = eidx_b + E;            // [E]

    const size_t ws_need = (size_t)((long)8960000 + 520002 + 2) * sizeof(float);
    if (ws_size < ws_need) return;

    // 1) zero deg_b/deg_f (2N ints = 10000 float4)
    zero_kernel<<<dim3((2 * N / 4 + 255) / 256), dim3(256), 0, stream>>>(
        (float4*)deg_b, (long)2 * N / 4);

    const int gE = (E + 255) / 256;

    // 2-4) CSR build, both directions per dispatch
    hist2_kernel<<<dim3(gE, 2), dim3(256), 0, stream>>>(
        bw_dst, fw_dst, deg_b, deg_f, E);
    scan2_kernel<<<dim3(2), dim3(1024), 0, stream>>>(
        deg_b, deg_f, rowptr_b, rowptr_f, cursor_b, cursor_f, N);
    scatter2_kernel<<<dim3(gE, 2), dim3(256), 0, stream>>>(
        bw_dst, fw_dst, cursor_b, cursor_f, eidx_b, eidx_f, E);

    // 5) five 64->64 node linears in one dispatch (8x8 tile, BR=128)
    {
        LinArgs a;
        a.x[0]=u_feat; a.W[0]=w_u;  a.bias[0]=b_u;  a.out[0]=src_he_u; a.ostride[0]=64;
        a.x[1]=v_feat; a.W[1]=w_v;  a.bias[1]=b_v;  a.out[1]=src_he_v; a.ostride[1]=64;
        a.x[2]=v_feat; a.W[2]=w_u;  a.bias[2]=b_u;  a.out[2]=dst_he_v; a.ostride[2]=64;
        a.x[3]=u_feat; a.W[3]=w_Vu; a.bias[3]=b_Vu; a.out[3]=hu;       a.ostride[3]=128;
        a.x[4]=v_feat; a.W[4]=w_Vv; a.bias[4]=b_Vv; a.out[4]=hv;       a.ostride[4]=128;
        lin8_kernel<64,false><<<dim3((N + 127) / 128, 5), dim3(128), 0, stream>>>(a, N);
    }

    // 6) two 64->128 attention projections in one dispatch (8x8 tile, BR=64)
    {
        LinArgs a = {};
        a.x[0]=u_feat; a.W[0]=w_au; a.bias[0]=b_au; a.out[0]=h_att_u; a.ostride[0]=128;
        a.x[1]=v_feat; a.W[1]=w_av; a.bias[1]=b_av; a.out[1]=h_att_v; a.ostride[1]=128;
        lin8_kernel<128,false><<<dim3((N + 63) / 64, 2), dim3(128), 0, stream>>>(a, N);
    }

    // 7) segmented attention aggregation v3, both directions, no atomics
    agg3_kernel<<<dim3(N, 2), dim3(128), 0, stream>>>(
        v_feat, b_feat, h_att_u, bw_src, eidx_b, rowptr_b, agg_u,
        u_feat, f_feat, h_att_v, fw_src, eidx_f, rowptr_f, agg_v);

    // 8) two 128->64 final linears in one dispatch (right halves of hu/hv)
    {
        LinArgs a = {};
        a.x[0]=agg_u; a.W[0]=w_Wu; a.bias[0]=b_Wu; a.out[0]=hu + 64; a.ostride[0]=128;
        a.x[1]=agg_v; a.W[1]=w_Wv; a.bias[1]=b_Wv; a.out[1]=hv + 64; a.ostride[1]=128;
        lin_small_kernel<128,64,128,true><<<dim3((N + 31) / 32, 2), dim3(128), 0, stream>>>(a, N);
    }

    // 9) edge outputs LAST (overwrite h_att scratch in hf):
    //    hf = relu(b_feat@w_e + b_e + src_he_u[bw_src] + src_he_v[bw_dst])
    //    hb = relu(f_feat@w_e + b_e + src_he_u[fw_src] + dst_he_v[fw_dst])
    {
        EdgeArgs a;
        a.x[0]=b_feat; a.tabA[0]=src_he_u; a.tabB[0]=src_he_v;
        a.idxA[0]=bw_src; a.idxB[0]=bw_dst; a.out[0]=hf;
        a.x[1]=f_feat; a.tabA[1]=src_he_u; a.tabB[1]=dst_he_v;
        a.idxA[1]=fw_src; a.idxB[1]=fw_dst; a.out[1]=hb;
        edge8_kernel<<<dim3((E + 127) / 128, 2), dim3(128), 0, stream>>>(a, w_e, b_e, E);
    }
}

// Round 3
// 486.032 us; speedup vs baseline: 1.0750x; 1.0750x over previous
//
#include <hip/hip_runtime.h>

#define NNODES 20000
#define NEDGES 200000

// ---------------------------------------------------------------------------
// Zero-fill (float4 granularity). n4 = number of float4 elements.
// ---------------------------------------------------------------------------
__global__ __launch_bounds__(256)
void zero_kernel(float4* __restrict__ p, long n4)
{
    long i = (long)blockIdx.x * 256 + threadIdx.x;
    if (i < n4) p[i] = make_float4(0.f, 0.f, 0.f, 0.f);
}

// ---------------------------------------------------------------------------
// CSR build, both directions batched via blockIdx.y / blockIdx.x(scan):
// histogram -> single-block-per-direction scan -> scatter
// ---------------------------------------------------------------------------
__global__ __launch_bounds__(256)
void hist2_kernel(const int* __restrict__ dst0, const int* __restrict__ dst1,
                  int* __restrict__ deg0, int* __restrict__ deg1, int n)
{
    const int e = blockIdx.x * 256 + threadIdx.x;
    if (e >= n) return;
    if (blockIdx.y == 0) atomicAdd(&deg0[dst0[e]], 1);
    else                 atomicAdd(&deg1[dst1[e]], 1);
}

__global__ __launch_bounds__(1024)
void scan2_kernel(const int* __restrict__ deg0, const int* __restrict__ deg1,
                  int* __restrict__ rp0, int* __restrict__ rp1,
                  int* __restrict__ cur0, int* __restrict__ cur1, int n)
{
    const int* deg = blockIdx.x == 0 ? deg0 : deg1;
    int* rowptr    = blockIdx.x == 0 ? rp0  : rp1;
    int* cursor    = blockIdx.x == 0 ? cur0 : cur1;

    __shared__ int part[1024];
    const int t  = threadIdx.x;
    const int CH = (n + 1023) / 1024;
    const int base = t * CH;

    int s = 0;
    for (int i = 0; i < CH; ++i) {
        int idx = base + i;
        if (idx < n) s += deg[idx];
    }
    part[t] = s;
    __syncthreads();
    for (int off = 1; off < 1024; off <<= 1) {
        int v = 0;
        if (t >= off) v = part[t - off];
        __syncthreads();
        if (t >= off) part[t] += v;
        __syncthreads();
    }
    int run = (t == 0) ? 0 : part[t - 1];
    for (int i = 0; i < CH; ++i) {
        int idx = base + i;
        if (idx < n) {
            int dv = deg[idx];
            rowptr[idx] = run;
            cursor[idx] = run;
            run += dv;
        }
    }
    if (t == 1023) rowptr[n] = part[1023];
}

__global__ __launch_bounds__(256)
void scatter2_kernel(const int* __restrict__ dst0, const int* __restrict__ dst1,
                     int* __restrict__ cur0, int* __restrict__ cur1,
                     int* __restrict__ ei0, int* __restrict__ ei1, int n)
{
    const int e = blockIdx.x * 256 + threadIdx.x;
    if (e >= n) return;
    if (blockIdx.y == 0) { int p = atomicAdd(&cur0[dst0[e]], 1); ei0[p] = e; }
    else                 { int p = atomicAdd(&cur1[dst1[e]], 1); ei1[p] = e; }
}

// ---------------------------------------------------------------------------
// Segmented attention-aggregation v3 (unchanged this round).
// ---------------------------------------------------------------------------
__global__ __launch_bounds__(128)
void agg3_kernel(const float* __restrict__ fn0, const float* __restrict__ fe0,
                 const float* __restrict__ ha0, const int* __restrict__ src0,
                 const int* __restrict__ ei0,  const int* __restrict__ rp0,
                 float* __restrict__ agg0,
                 const float* __restrict__ fn1, const float* __restrict__ fe1,
                 const float* __restrict__ ha1, const int* __restrict__ src1,
                 const int* __restrict__ ei1,  const int* __restrict__ rp1,
                 float* __restrict__ agg1)
{
    const int y = blockIdx.y;
    const float* __restrict__ feat_node = y == 0 ? fn0 : fn1;
    const float* __restrict__ feat_edge = y == 0 ? fe0 : fe1;
    const float* __restrict__ h_att     = y == 0 ? ha0 : ha1;
    const int*   __restrict__ src       = y == 0 ? src0 : src1;
    const int*   __restrict__ eidx      = y == 0 ? ei0 : ei1;
    const int*   __restrict__ rowptr    = y == 0 ? rp0 : rp1;
    float*       __restrict__ agg       = y == 0 ? agg0 : agg1;

    const int d = blockIdx.x;
    const int c = threadIdx.x;
    const int lo = rowptr[d], hi = rowptr[d + 1];
    const bool low = c < 64;

    __shared__ int se[64];
    __shared__ int ss[64];

    float ssum = 0.f, anum = 0.f;

    for (int base = lo; base < hi; base += 64) {
        const int cnt = min(64, hi - base);
        if (c < cnt) {
            const int e = eidx[base + c];
            se[c] = e;
            ss[c] = src[e];
        }
        __syncthreads();

        int i = 0;
        for (; i + 4 <= cnt; i += 4) {
            float hv[4], at[4];
            #pragma unroll
            for (int j = 0; j < 4; ++j) {
                const int e = se[i + j];
                const int s = ss[i + j];
                hv[j] = low ? feat_node[(long)s * 64 + c]
                            : feat_edge[(long)e * 64 + (c - 64)];
                at[j] = h_att[(long)s * 128 + c];
            }
            #pragma unroll
            for (int j = 0; j < 4; ++j) {
                const float p = __expf(hv[j] * at[j]);
                ssum += p;
                anum += hv[j] * p;
            }
        }
        for (; i < cnt; ++i) {
            const int e = se[i];
            const int s = ss[i];
            const float hvv = low ? feat_node[(long)s * 64 + c]
                                  : feat_edge[(long)e * 64 + (c - 64)];
            const float att = h_att[(long)s * 128 + c];
            const float p = __expf(hvv * att);
            ssum += p;
            anum += hvv * p;
        }
        __syncthreads();
    }
    agg[(long)d * 128 + c] = (hi > lo) ? anum / ssum : 0.f;
}

// ---------------------------------------------------------------------------
// Round-8 GEMM microkernel family: 8x4 per-thread micro-tile, BLOCK=256.
// Evidence trail:
//   r0: 4x4 @12 waves/CU -> issue-mix-bound (VALU 44%, 5 LDS instr / 16 FMA)
//   r1: occupancy 73% alone didn't help -> not wave-starved at 4x4
//   r2: 8x8 @~5 waves/CU -> latency-bound (VALU 26%), but LDS layouts proven
//       conflict-free (5.6M -> 400K)
// 8x4 @256 threads keeps 12 waves/CU (50.4 KB LDS, 3 blocks/CU) AND improves
// the mix to 12 LDS instr / 128 FMA per k-quad (~91% of issue slots = FMA).
// x: k-quad slabs xs4[kv][slot], slot(rr)=(rr&3)*BQ+(rr>>2) -> b128 reads are
// 16-lane broadcasts at 4 distinct bank-groups; W rows padded (+4 floats).
// ---------------------------------------------------------------------------
struct LinArgs {
    const float* x[5];
    const float* W[5];
    const float* bias[5];
    float*       out[5];
    long         ostride[5];
};

template<int DOUT, bool RELU>
__global__ __launch_bounds__(256)
void lin84_kernel(LinArgs a, int nrows)
{
    constexpr int BLOCK = 256;
    constexpr int DIN = 64;
    constexpr int KV  = DIN / 4;        // 16 k-quads
    constexpr int JT  = DOUT / 4;       // col groups: 16 (DOUT=64) / 32 (128)
    constexpr int RT  = BLOCK / JT;     // row groups: 16 / 8
    constexpr int BR  = RT * 8;         // rows/block: 128 / 64
    constexpr int BQ  = BR / 4;         // row-quads: 32 / 16
    constexpr int XSTR = BR + 1;        // float4 stride per kv slab
    constexpr int WSTR = DOUT + 4;      // float stride per W row
    constexpr int NC4 = DOUT / 4;

    const int y = blockIdx.y;
    const float* __restrict__ x    = a.x[y];
    const float* __restrict__ W    = a.W[y];
    const float* __restrict__ bias = a.bias[y];
    float* __restrict__ out        = a.out[y];
    const long ostride             = a.ostride[y];

    __shared__ float4 xs4[KV * XSTR];
    __shared__ float  Ws[DIN * WSTR];

    const int tid  = threadIdx.x;
    const int row0 = blockIdx.x * BR;

    // stage W (row padded by 1 float4 -> read conflicts <= 2-4 way, negligible)
    const float4* __restrict__ W4 = (const float4*)W;
    for (int i = tid; i < DIN * NC4; i += BLOCK) {
        const int k = i / NC4, c4 = i % NC4;
        ((float4*)(Ws + k * WSTR))[c4] = W4[i];
    }
    // stage x (k-quad slabs, row-slot permute); coalesced global reads
    const float4* __restrict__ X4 = (const float4*)x;
    for (int i = tid; i < BR * KV; i += BLOCK) {
        const int rr = i >> 4, kv = i & 15;
        const int row = row0 + rr;
        float4 v = make_float4(0.f, 0.f, 0.f, 0.f);
        if (row < nrows) v = X4[(long)row * KV + kv];
        xs4[kv * XSTR + (rr & 3) * BQ + (rr >> 2)] = v;
    }
    __syncthreads();

    const int jt = tid % JT;
    const int rt = tid / JT;

    float4 b4 = ((const float4*)bias)[jt];
    float acc[8][4];
    #pragma unroll
    for (int r = 0; r < 8; ++r) {
        acc[r][0] = b4.x; acc[r][1] = b4.y; acc[r][2] = b4.z; acc[r][3] = b4.w;
    }

    #pragma unroll 2
    for (int kv = 0; kv < KV; ++kv) {
        float4 xq[8];
        #pragma unroll
        for (int r = 0; r < 8; ++r)
            xq[r] = xs4[kv * XSTR + (r & 3) * BQ + rt * 2 + (r >> 2)];
        #pragma unroll
        for (int q = 0; q < 4; ++q) {
            const int k = kv * 4 + q;
            float4 w = ((const float4*)(Ws + k * WSTR))[jt];
            #pragma unroll
            for (int r = 0; r < 8; ++r) {
                const float xk = q == 0 ? xq[r].x : q == 1 ? xq[r].y
                               : q == 2 ? xq[r].z : xq[r].w;
                acc[r][0] = fmaf(xk, w.x, acc[r][0]);
                acc[r][1] = fmaf(xk, w.y, acc[r][1]);
                acc[r][2] = fmaf(xk, w.z, acc[r][2]);
                acc[r][3] = fmaf(xk, w.w, acc[r][3]);
            }
        }
    }

    #pragma unroll
    for (int r = 0; r < 8; ++r) {
        const int row = row0 + rt * 8 + r;
        if (row >= nrows) continue;
        float4 o = make_float4(acc[r][0], acc[r][1], acc[r][2], acc[r][3]);
        if (RELU) {
            o.x = fmaxf(o.x, 0.f); o.y = fmaxf(o.y, 0.f);
            o.z = fmaxf(o.z, 0.f); o.w = fmaxf(o.w, 0.f);
        }
        *((float4*)(out + (long)row * ostride) + jt) = o;
    }
}

// ---------------------------------------------------------------------------
// Edge kernel, same 8x4 structure (DIN=DOUT=64) + gather epilogue:
//   out = relu(x @ W + b + tabA[idxA[r]] + tabB[idxB[r]])
// ---------------------------------------------------------------------------
struct EdgeArgs {
    const float* x[2];
    const float* tabA[2];
    const float* tabB[2];
    const int*   idxA[2];
    const int*   idxB[2];
    float*       out[2];
};

__global__ __launch_bounds__(256)
void edge84_kernel(EdgeArgs a, const float* __restrict__ W,
                   const float* __restrict__ bias, int nrows)
{
    constexpr int BLOCK = 256;
    constexpr int DIN = 64, DOUT = 64;
    constexpr int KV  = 16;
    constexpr int JT  = 16;
    constexpr int BR  = 128;
    constexpr int BQ  = 32;
    constexpr int XSTR = BR + 1;    // 129 float4s
    constexpr int WSTR = DOUT + 4;  // 68
    constexpr int NC4 = 16;

    const int y = blockIdx.y;
    const float* __restrict__ x    = a.x[y];
    const float* __restrict__ tabA = a.tabA[y];
    const float* __restrict__ tabB = a.tabB[y];
    const int* __restrict__ idxA   = a.idxA[y];
    const int* __restrict__ idxB   = a.idxB[y];
    float* __restrict__ out        = a.out[y];

    __shared__ float4 xs4[KV * XSTR];
    __shared__ float  Ws[DIN * WSTR];

    const int tid  = threadIdx.x;
    const int row0 = blockIdx.x * BR;

    const float4* __restrict__ W4 = (const float4*)W;
    for (int i = tid; i < DIN * NC4; i += BLOCK) {
        const int k = i / NC4, c4 = i % NC4;
        ((float4*)(Ws + k * WSTR))[c4] = W4[i];
    }
    const float4* __restrict__ X4 = (const float4*)x;
    for (int i = tid; i < BR * KV; i += BLOCK) {
        const int rr = i >> 4, kv = i & 15;
        const int row = row0 + rr;
        float4 v = make_float4(0.f, 0.f, 0.f, 0.f);
        if (row < nrows) v = X4[(long)row * KV + kv];
        xs4[kv * XSTR + (rr & 3) * BQ + (rr >> 2)] = v;
    }
    __syncthreads();

    const int jt = tid % JT;
    const int rt = tid / JT;

    float4 b4 = ((const float4*)bias)[jt];
    float acc[8][4];
    #pragma unroll
    for (int r = 0; r < 8; ++r) {
        acc[r][0] = b4.x; acc[r][1] = b4.y; acc[r][2] = b4.z; acc[r][3] = b4.w;
    }

    #pragma unroll 2
    for (int kv = 0; kv < KV; ++kv) {
        float4 xq[8];
        #pragma unroll
        for (int r = 0; r < 8; ++r)
            xq[r] = xs4[kv * XSTR + (r & 3) * BQ + rt * 2 + (r >> 2)];
        #pragma unroll
        for (int q = 0; q < 4; ++q) {
            const int k = kv * 4 + q;
            float4 w = ((const float4*)(Ws + k * WSTR))[jt];
            #pragma unroll
            for (int r = 0; r < 8; ++r) {
                const float xk = q == 0 ? xq[r].x : q == 1 ? xq[r].y
                               : q == 2 ? xq[r].z : xq[r].w;
                acc[r][0] = fmaf(xk, w.x, acc[r][0]);
                acc[r][1] = fmaf(xk, w.y, acc[r][1]);
                acc[r][2] = fmaf(xk, w.z, acc[r][2]);
                acc[r][3] = fmaf(xk, w.w, acc[r][3]);
            }
        }
    }

    // epilogue: issue all idx loads first, then per-row gathers + store
    int ia[8], ib[8];
    #pragma unroll
    for (int r = 0; r < 8; ++r) {
        const int row = row0 + rt * 8 + r;
        ia[r] = (row < nrows) ? idxA[row] : 0;
        ib[r] = (row < nrows) ? idxB[row] : 0;
    }
    #pragma unroll
    for (int r = 0; r < 8; ++r) {
        const int row = row0 + rt * 8 + r;
        if (row >= nrows) continue;
        float4 ga = ((const float4*)(tabA + (long)ia[r] * 64))[jt];
        float4 gb = ((const float4*)(tabB + (long)ib[r] * 64))[jt];
        float4 o;
        o.x = fmaxf(acc[r][0] + ga.x + gb.x, 0.f);
        o.y = fmaxf(acc[r][1] + ga.y + gb.y, 0.f);
        o.z = fmaxf(acc[r][2] + ga.z + gb.z, 0.f);
        o.w = fmaxf(acc[r][3] + ga.w + gb.w, 0.f);
        *((float4*)(out + (long)row * 64) + jt) = o;
    }
}

// ---------------------------------------------------------------------------
// Small 4x4 template for the 128->64 final linear. W from global
// (L1-resident), xs col-major stride BR+1, 4x b32 broadcast reads.
// ---------------------------------------------------------------------------
template<int DIN, int DOUT, int BLOCK, bool RELU>
__global__ __launch_bounds__(BLOCK)
void lin_small_kernel(LinArgs a, int nrows)
{
    constexpr int BR  = 16 * BLOCK / DOUT;   // 32 for <128,64,128>
    constexpr int BRP = BR + 1;
    constexpr int KV  = DIN / 4;
    constexpr int JT  = DOUT / 4;

    const int y = blockIdx.y;
    const float* __restrict__ x    = a.x[y];
    const float* __restrict__ W    = a.W[y];
    const float* __restrict__ bias = a.bias[y];
    float* __restrict__ out        = a.out[y];
    const long ostride             = a.ostride[y];

    __shared__ float xs[DIN * BRP];

    const int tid  = threadIdx.x;
    const int row0 = blockIdx.x * BR;

    const int kv = tid % KV;
    for (int rr = tid / KV; rr < BR; rr += BLOCK / KV) {
        const int row = row0 + rr;
        float4 v = make_float4(0.f, 0.f, 0.f, 0.f);
        if (row < nrows)
            v = ((const float4*)x)[(long)row * KV + kv];
        xs[(kv * 4 + 0) * BRP + rr] = v.x;
        xs[(kv * 4 + 1) * BRP + rr] = v.y;
        xs[(kv * 4 + 2) * BRP + rr] = v.z;
        xs[(kv * 4 + 3) * BRP + rr] = v.w;
    }
    __syncthreads();

    const int jt = tid % JT;
    const int rt = tid / JT;

    float4 b4 = ((const float4*)bias)[jt];
    float acc[4][4];
    #pragma unroll
    for (int r = 0; r < 4; ++r) {
        acc[r][0] = b4.x; acc[r][1] = b4.y; acc[r][2] = b4.z; acc[r][3] = b4.w;
    }

    const float4* __restrict__ W4 = (const float4*)W;
    #pragma unroll 4
    for (int k = 0; k < DIN; ++k) {
        float4 w = W4[k * JT + jt];
        float xr[4];
        #pragma unroll
        for (int r = 0; r < 4; ++r) xr[r] = xs[k * BRP + rt * 4 + r];
        #pragma unroll
        for (int r = 0; r < 4; ++r) {
            acc[r][0] = fmaf(xr[r], w.x, acc[r][0]);
            acc[r][1] = fmaf(xr[r], w.y, acc[r][1]);
            acc[r][2] = fmaf(xr[r], w.z, acc[r][2]);
            acc[r][3] = fmaf(xr[r], w.w, acc[r][3]);
        }
    }

    #pragma unroll
    for (int r = 0; r < 4; ++r) {
        const int row = row0 + rt * 4 + r;
        if (row >= nrows) continue;
        float4 o = make_float4(acc[r][0], acc[r][1], acc[r][2], acc[r][3]);
        if (RELU) {
            o.x = fmaxf(o.x, 0.f); o.y = fmaxf(o.y, 0.f);
            o.z = fmaxf(o.z, 0.f); o.w = fmaxf(o.w, 0.f);
        }
        *((float4*)(out + (long)row * ostride) + jt) = o;
    }
}

// ---------------------------------------------------------------------------
extern "C" void kernel_launch(void* const* d_in, const int* in_sizes, int n_in,
                              void* d_out, int out_size, void* d_ws, size_t ws_size,
                              hipStream_t stream)
{
    const float* f_feat = (const float*)d_in[0];
    const float* b_feat = (const float*)d_in[1];
    const float* u_feat = (const float*)d_in[2];
    const float* v_feat = (const float*)d_in[3];
    const int* fw_src = (const int*)d_in[4];
    const int* fw_dst = (const int*)d_in[5];
    const int* bw_src = (const int*)d_in[6];
    const int* bw_dst = (const int*)d_in[7];
    const float* w_e  = (const float*)d_in[8];   const float* b_e  = (const float*)d_in[9];
    const float* w_u  = (const float*)d_in[10];  const float* b_u  = (const float*)d_in[11];
    const float* w_v  = (const float*)d_in[12];  const float* b_v  = (const float*)d_in[13];
    const float* w_au = (const float*)d_in[14];  const float* b_au = (const float*)d_in[15];
    const float* w_av = (const float*)d_in[16];  const float* b_av = (const float*)d_in[17];
    const float* w_Wu = (const float*)d_in[18];  const float* b_Wu = (const float*)d_in[19];
    const float* w_Wv = (const float*)d_in[20];  const float* b_Wv = (const float*)d_in[21];
    const float* w_Vu = (const float*)d_in[22];  const float* b_Vu = (const float*)d_in[23];
    const float* w_Vv = (const float*)d_in[24];  const float* b_Vv = (const float*)d_in[25];

    const int N = NNODES, E = NEDGES;

    // outputs: (hf, hb, hu, hv) concatenated flat
    float* out = (float*)d_out;
    float* hf = out;                       // [E,64]  (written LAST)
    float* hb = hf + (long)E * 64;         // [E,64]  (written LAST)
    float* hu = hb + (long)E * 64;         // [N,128]
    float* hv = hu + (long)N * 128;        // [N,128]

    // h_att_u / h_att_v staged in the hf region of d_out (2*N*128 floats
    // < E*64). Consumed by agg, then hf overwritten by the edge batch LAST.
    float* h_att_u = hf;                   // [N,128]
    float* h_att_v = h_att_u + (long)N * 128;

    // workspace: floats 3*N*64 + 2*N*128 = 8.96M; ints 6N+2+2E = 0.52M
    float* ws = (float*)d_ws;
    float* src_he_u = ws;                        // [N,64] (== dst_he_u)
    float* src_he_v = src_he_u + (long)N * 64;   // [N,64]
    float* dst_he_v = src_he_v + (long)N * 64;   // [N,64]
    float* agg_u    = dst_he_v + (long)N * 64;   // [N,128]
    float* agg_v    = agg_u    + (long)N * 128;  // [N,128]
    int*   ibase    = (int*)(agg_v + (long)N * 128);
    int* deg_b    = ibase;                 // [N] zeroed
    int* deg_f    = deg_b + N;             // [N] zeroed
    int* rowptr_b = deg_f + N;             // [N+1]
    int* rowptr_f = rowptr_b + (N + 1);    // [N+1]
    int* cursor_b = rowptr_f + (N + 1);    // [N]
    int* cursor_f = cursor_b + N;          // [N]
    int* eidx_b   = cursor_f + N;          // [E]
    int* eidx_f   = eidx_b + E;            // [E]

    const size_t ws_need = (size_t)((long)8960000 + 520002 + 2) * sizeof(float);
    if (ws_size < ws_need) return;

    // 1) zero deg_b/deg_f (2N ints = 10000 float4)
    zero_kernel<<<dim3((2 * N / 4 + 255) / 256), dim3(256), 0, stream>>>(
        (float4*)deg_b, (long)2 * N / 4);

    const int gE = (E + 255) / 256;

    // 2-4) CSR build, both directions per dispatch
    hist2_kernel<<<dim3(gE, 2), dim3(256), 0, stream>>>(
        bw_dst, fw_dst, deg_b, deg_f, E);
    scan2_kernel<<<dim3(2), dim3(1024), 0, stream>>>(
        deg_b, deg_f, rowptr_b, rowptr_f, cursor_b, cursor_f, N);
    scatter2_kernel<<<dim3(gE, 2), dim3(256), 0, stream>>>(
        bw_dst, fw_dst, cursor_b, cursor_f, eidx_b, eidx_f, E);

    // 5) five 64->64 node linears in one dispatch (8x4 tile, BR=128)
    {
        LinArgs a;
        a.x[0]=u_feat; a.W[0]=w_u;  a.bias[0]=b_u;  a.out[0]=src_he_u; a.ostride[0]=64;
        a.x[1]=v_feat; a.W[1]=w_v;  a.bias[1]=b_v;  a.out[1]=src_he_v; a.ostride[1]=64;
        a.x[2]=v_feat; a.W[2]=w_u;  a.bias[2]=b_u;  a.out[2]=dst_he_v; a.ostride[2]=64;
        a.x[3]=u_feat; a.W[3]=w_Vu; a.bias[3]=b_Vu; a.out[3]=hu;       a.ostride[3]=128;
        a.x[4]=v_feat; a.W[4]=w_Vv; a.bias[4]=b_Vv; a.out[4]=hv;       a.ostride[4]=128;
        lin84_kernel<64,false><<<dim3((N + 127) / 128, 5), dim3(256), 0, stream>>>(a, N);
    }

    // 6) two 64->128 attention projections in one dispatch (8x4 tile, BR=64)
    {
        LinArgs a = {};
        a.x[0]=u_feat; a.W[0]=w_au; a.bias[0]=b_au; a.out[0]=h_att_u; a.ostride[0]=128;
        a.x[1]=v_feat; a.W[1]=w_av; a.bias[1]=b_av; a.out[1]=h_att_v; a.ostride[1]=128;
        lin84_kernel<128,false><<<dim3((N + 63) / 64, 2), dim3(256), 0, stream>>>(a, N);
    }

    // 7) segmented attention aggregation v3, both directions, no atomics
    agg3_kernel<<<dim3(N, 2), dim3(128), 0, stream>>>(
        v_feat, b_feat, h_att_u, bw_src, eidx_b, rowptr_b, agg_u,
        u_feat, f_feat, h_att_v, fw_src, eidx_f, rowptr_f, agg_v);

    // 8) two 128->64 final linears in one dispatch (right halves of hu/hv)
    {
        LinArgs a = {};
        a.x[0]=agg_u; a.W[0]=w_Wu; a.bias[0]=b_Wu; a.out[0]=hu + 64; a.ostride[0]=128;
        a.x[1]=agg_v; a.W[1]=w_Wv; a.bias[1]=b_Wv; a.out[1]=hv + 64; a.ostride[1]=128;
        lin_small_kernel<128,64,128,true><<<dim3((N + 31) / 32, 2), dim3(128), 0, stream>>>(a, N);
    }

    // 9) edge outputs LAST (overwrite h_att scratch in hf):
    //    hf = relu(b_feat@w_e + b_e + src_he_u[bw_src] + src_he_v[bw_dst])
    //    hb = relu(f_feat@w_e + b_e + src_he_u[fw_src] + dst_he_v[fw_dst])
    {
        EdgeArgs a;
        a.x[0]=b_feat; a.tabA[0]=src_he_u; a.tabB[0]=src_he_v;
        a.idxA[0]=bw_src; a.idxB[0]=bw_dst; a.out[0]=hf;
        a.x[1]=f_feat; a.tabA[1]=src_he_u; a.tabB[1]=dst_he_v;
        a.idxA[1]=fw_src; a.idxB[1]=fw_dst; a.out[1]=hb;
        edge84_kernel<<<dim3((E + 127) / 128, 2), dim3(256), 0, stream>>>(a, w_e, b_e, E);
    }
}